// Round 8
// baseline (154.284 us; speedup 1.0000x reference)
//
#include <hip/hip_runtime.h>

typedef unsigned long long u64;

#define N_ROIS 2048
#define N_CLSX 21
#define N_CLS_OUT 20
#define SCORE_T 0.3f
#define NMS_T 0.3f
#define DEDUP_T 0.3f
#define NT 256
#define NWAVES (NT / 64)
#define CPW (N_ROIS / 64 / NWAVES)   // 8 chunks of 64 rois per wave
#define NFAST 128                    // register-path bound (2 slots/lane)

__device__ __forceinline__ float iou_f(float ax1, float ay1, float ax2, float ay2,
                                       float aarea,
                                       float bx1, float by1, float bx2, float by2,
                                       float barea) {
    float ix1 = fmaxf(ax1, bx1), iy1 = fmaxf(ay1, by1);
    float ix2 = fminf(ax2, bx2), iy2 = fminf(ay2, by2);
    float iw = fmaxf(ix2 - ix1, 0.0f), ih = fmaxf(iy2 - iy1, 0.0f);
    float inter = iw * ih;
    return inter / (aarea + barea - inter + 1e-6f);
}

__global__ __launch_bounds__(NT) void detect_kernel(
    const float* __restrict__ rois,      // (2048,5)
    const float* __restrict__ cls_prob,  // (2048,21)
    const float* __restrict__ bbox_pred, // (2048,84)
    const float* __restrict__ im_info,   // (3,)
    const float* __restrict__ gt_boxes,  // (50,5)
    const int*   __restrict__ num_boxes,
    float* __restrict__ out)             // (20,2048,5)
{
    __shared__ float  vsc[N_ROIS];
    __shared__ int    vidx[N_ROIS];
    __shared__ float4 sbox[N_ROIS];
    __shared__ float  ssc[N_ROIS];
    __shared__ unsigned char keepb[N_ROIS];    // fallback only
    __shared__ float4 sgt[64];
    __shared__ int    wbase[NWAVES];
    __shared__ float  rsc[NFAST];
    __shared__ int    ridx[NFAST];
    __shared__ u64    kwords[2];
    __shared__ u64    dupw[2];

    const int tid = threadIdx.x;
    const int wid = tid >> 6, lane = tid & 63;
    const int cls = blockIdx.x + 1;
    const int ng = *num_boxes;
    const float W = im_info[1], H = im_info[0];
    float* o = out + (size_t)blockIdx.x * N_ROIS * 5;

    // ---- phase 1: compact straight from global (independent strided loads)
    u64 masks[CPW];
    float vals[CPW];
    int mycnt = 0;
    #pragma unroll
    for (int c = 0; c < CPW; ++c) {
        int i = ((wid * CPW + c) << 6) + lane;
        float sc = cls_prob[i * N_CLSX + cls];
        vals[c] = sc;
        masks[c] = __ballot(sc > SCORE_T);
        mycnt += __popcll(masks[c]);
    }
    if (lane == 0) wbase[wid] = mycnt;
    __syncthreads();                               // B1
    int base = 0;
    for (int w = 0; w < wid; ++w) base += wbase[w];
    int nvtot = 0;
    for (int w = 0; w < NWAVES; ++w) nvtot += wbase[w];
    const int nv = nvtot;
    #pragma unroll
    for (int c = 0; c < CPW; ++c) {
        int i = ((wid * CPW + c) << 6) + lane;
        u64 m = masks[c];
        if ((m >> lane) & 1ULL) {
            int pre = __popcll(m & ((1ULL << lane) - 1ULL));
            vidx[base + pre] = i;
            vsc[base + pre]  = vals[c];
        }
        base += __popcll(m);
    }
    __syncthreads();                               // B2

    if (nv <= NFAST) {
        // ================= FAST PATH: one-wave register NMS =================
        float4 b0 = make_float4(0,0,0,0), b1 = make_float4(0,0,0,0);
        if (wid == 0) {
            // rank via shfl count-loop; then decode within the same wave
            float s0 = (lane < nv)      ? vsc[lane]      : 0.0f;
            float s1 = (64 + lane < nv) ? vsc[64 + lane] : 0.0f;
            int r0 = 0, r1 = 0;
            const int n0 = nv < 64 ? nv : 64;
            for (int u = 0; u < n0; ++u) {
                float su0 = __shfl(s0, u);
                float su1 = __shfl(s1, u);
                r0 += (su0 > s0) || (su0 == s0 && u < lane);
                r1 += (su0 > s1) || (su0 == s1);
                if (64 + u < nv) {
                    r0 += (su1 > s0);
                    r1 += (su1 > s1) || (su1 == s1 && u < lane);
                }
            }
            if (lane < nv)      { rsc[r0] = s0; ridx[r0] = vidx[lane]; }
            if (64 + lane < nv) { rsc[r1] = s1; ridx[r1] = vidx[64 + lane]; }
            // same-wave LDS readback (no block barrier needed)
            int e0 = lane, e1 = 64 + lane;
            int idx0 = (e0 < nv) ? ridx[e0] : 0;
            int idx1 = (e1 < nv) ? ridx[e1] : 0;
            float sc0 = (e0 < nv) ? rsc[e0] : 0.0f;
            float sc1 = (e1 < nv) ? rsc[e1] : 0.0f;
            #define DECODE(IDX, B)                                            \
            {                                                                 \
                float x1 = rois[(IDX) * 5 + 1], y1 = rois[(IDX) * 5 + 2];     \
                float x2 = rois[(IDX) * 5 + 3], y2 = rois[(IDX) * 5 + 4];     \
                const float* dp = &bbox_pred[(IDX) * 84 + cls * 4];           \
                float d0 = dp[0], d1 = dp[1], d2 = dp[2], d3 = dp[3];         \
                float w = x2 - x1 + 1.0f, h = y2 - y1 + 1.0f;                 \
                float cx = x1 + 0.5f * w, cy = y1 + 0.5f * h;                 \
                float pcx = d0 * 0.1f * w + cx, pcy = d1 * 0.1f * h + cy;     \
                float pw = expf(d2 * 0.2f) * w, ph = expf(d3 * 0.2f) * h;     \
                B.x = fminf(fmaxf(pcx - 0.5f * pw, 0.0f), W - 1.0f);          \
                B.y = fminf(fmaxf(pcy - 0.5f * ph, 0.0f), H - 1.0f);          \
                B.z = fminf(fmaxf(pcx + 0.5f * pw, 0.0f), W - 1.0f);          \
                B.w = fminf(fmaxf(pcy + 0.5f * ph, 0.0f), H - 1.0f);          \
            }
            DECODE(idx0, b0)
            DECODE(idx1, b1)
            if (e0 < nv) { sbox[e0] = b0; ssc[e0] = sc0; }
            if (e1 < nv) { sbox[e1] = b1; ssc[e1] = sc1; }
        } else {
            // waves 1-3: stage gt + zero-fill output with independent stores
            if (wid == 3)
                for (int g = lane; g < ng; g += 64)
                    sgt[g] = make_float4(gt_boxes[g * 5 + 0], gt_boxes[g * 5 + 1],
                                         gt_boxes[g * 5 + 2], gt_boxes[g * 5 + 3]);
            float4* o4 = (float4*)o;                 // 2560 float4 per class
            float4 z4 = make_float4(0.f, 0.f, 0.f, 0.f);
            for (int t = (wid - 1) * 64 + lane; t < N_ROIS * 5 / 4; t += 192)
                o4[t] = z4;
        }
        __syncthreads();                             // B3 (sbox/sgt ready)

        if (wid == 0) {
            // suppressor masks S (col-major: bits i that suppress my rank)
            float ar0 = (b0.z - b0.x) * (b0.w - b0.y);
            float ar1 = (b1.z - b1.x) * (b1.w - b1.y);
            u64 S0lo = 0, S0hi = 0, S1lo = 0, S1hi = 0;
            for (int i = 0; i < nv; ++i) {
                bool hi = i >= 64;
                int src = i & 63;
                float cx1 = __shfl(hi ? b1.x : b0.x, src);
                float cy1 = __shfl(hi ? b1.y : b0.y, src);
                float cx2 = __shfl(hi ? b1.z : b0.z, src);
                float cy2 = __shfl(hi ? b1.w : b0.w, src);
                float car = __shfl(hi ? ar1 : ar0, src);
                float i0 = iou_f(cx1, cy1, cx2, cy2, car, b0.x, b0.y, b0.z, b0.w, ar0);
                float i1 = iou_f(cx1, cy1, cx2, cy2, car, b1.x, b1.y, b1.z, b1.w, ar1);
                bool sup0 = (i0 > NMS_T) && (i < lane);        // rank(slot0)=lane
                bool sup1 = (i1 > NMS_T) && (i < 64 + lane);   // rank(slot1)=64+lane
                if (i < 64) {
                    S0lo |= sup0 ? (1ULL << i) : 0ULL;
                    S1lo |= sup1 ? (1ULL << i) : 0ULL;
                } else {
                    S0hi |= sup0 ? (1ULL << (i - 64)) : 0ULL;
                    S1hi |= sup1 ? (1ULL << (i - 64)) : 0ULL;
                }
            }
            // Jacobi forward-substitution to the unique greedy fixpoint.
            // Converges in suppression-chain depth iterations (typ. <5).
            bool init0 = lane < nv, init1 = 64 + lane < nv;
            u64 kw0 = __ballot(init0), kw1 = __ballot(init1);
            for (int it = 0; it < NFAST; ++it) {
                bool a0 = init0 && !((S0lo & kw0) | (S0hi & kw1));
                bool a1 = init1 && !((S1lo & kw0) | (S1hi & kw1));
                u64 nk0 = __ballot(a0), nk1 = __ballot(a1);
                bool done = (nk0 == kw0) && (nk1 == kw1);
                kw0 = nk0; kw1 = nk1;
                if (done) break;
            }
            if (lane == 0) { kwords[0] = kw0; kwords[1] = kw1; }
        } else if (wid == 1 || wid == 2) {
            // GT dedup in parallel (ranks 0-63 on wave1, 64-127 on wave2)
            int e = (wid - 1) * 64 + lane;
            bool dup = false;
            if (e < nv) {
                float4 a = sbox[e];
                float aarea = (a.z - a.x) * (a.w - a.y);
                for (int g = 0; g < ng; ++g) {
                    float4 gb = sgt[g];
                    float garea = (gb.z - gb.x) * (gb.w - gb.y);
                    dup |= iou_f(a.x, a.y, a.z, a.w, aarea,
                                 gb.x, gb.y, gb.z, gb.w, garea) > DEDUP_T;
                }
            }
            u64 wd = __ballot(dup);
            if (lane == 0) dupw[wid - 1] = wd;
        }
        __syncthreads();                             // B4

        // kept-row write (zero-fill already covered everything else)
        if (tid < NFAST && tid < nv) {
            bool kept = ((kwords[tid >> 6] >> (tid & 63)) & 1ULL) &&
                        !((dupw[tid >> 6] >> (tid & 63)) & 1ULL);
            if (kept) {
                float4 b = sbox[tid];
                float s = ssc[tid];
                float* orow = o + tid * 5;
                orow[0] = b.x; orow[1] = b.y; orow[2] = b.z; orow[3] = b.w;
                orow[4] = s;
            }
        }
        return;
    }

    // ========== FALLBACK (nv > 128): compact barrier-per-row greedy ==========
    for (int g = tid; g < ng; g += NT)
        sgt[g] = make_float4(gt_boxes[g * 5 + 0], gt_boxes[g * 5 + 1],
                             gt_boxes[g * 5 + 2], gt_boxes[g * 5 + 3]);

    for (int v = tid; v < nv; v += NT) {
        int idx = vidx[v];
        float x1 = rois[idx * 5 + 1], y1 = rois[idx * 5 + 2];
        float x2 = rois[idx * 5 + 3], y2 = rois[idx * 5 + 4];
        const float* dp = &bbox_pred[idx * 84 + cls * 4];
        float d0 = dp[0], d1 = dp[1], d2 = dp[2], d3 = dp[3];
        float sc = vsc[v];
        int r = 0;
        for (int u = 0; u < nv; ++u) {
            float su = vsc[u];
            r += (su > sc) || (su == sc && u < v);
        }
        float w = x2 - x1 + 1.0f, h = y2 - y1 + 1.0f;
        float cx = x1 + 0.5f * w, cy = y1 + 0.5f * h;
        float pcx = d0 * 0.1f * w + cx, pcy = d1 * 0.1f * h + cy;
        float pw = expf(d2 * 0.2f) * w, ph = expf(d3 * 0.2f) * h;
        float4 b;
        b.x = fminf(fmaxf(pcx - 0.5f * pw, 0.0f), W - 1.0f);
        b.y = fminf(fmaxf(pcy - 0.5f * ph, 0.0f), H - 1.0f);
        b.z = fminf(fmaxf(pcx + 0.5f * pw, 0.0f), W - 1.0f);
        b.w = fminf(fmaxf(pcy + 0.5f * ph, 0.0f), H - 1.0f);
        sbox[r] = b;
        ssc[r]  = sc;
        keepb[r] = 1;
    }
    __syncthreads();

    for (int i = 0; i < nv; ++i) {
        __syncthreads();
        if (keepb[i]) {
            float4 a = sbox[i];
            float aarea = (a.z - a.x) * (a.w - a.y);
            for (int j = i + 1 + tid; j < nv; j += NT) {
                if (keepb[j]) {
                    float4 bb = sbox[j];
                    float barea = (bb.z - bb.x) * (bb.w - bb.y);
                    if (iou_f(a.x, a.y, a.z, a.w, aarea,
                              bb.x, bb.y, bb.z, bb.w, barea) > NMS_T)
                        keepb[j] = 0;
                }
            }
        }
    }
    __syncthreads();
    for (int v = tid; v < nv; v += NT) {
        if (keepb[v]) {
            float4 a = sbox[v];
            float aarea = (a.z - a.x) * (a.w - a.y);
            bool dup = false;
            for (int g = 0; g < ng; ++g) {
                float4 gb = sgt[g];
                float garea = (gb.z - gb.x) * (gb.w - gb.y);
                dup |= iou_f(a.x, a.y, a.z, a.w, aarea,
                             gb.x, gb.y, gb.z, gb.w, garea) > DEDUP_T;
            }
            if (dup) keepb[v] = 0;
        }
    }
    __syncthreads();
    for (int t = tid; t < N_ROIS * 5; t += NT) {
        int j = t / 5, comp = t - 5 * j;
        float val = 0.0f;
        if (j < nv && keepb[j]) {
            float4 b = sbox[j];
            val = comp == 0 ? b.x : comp == 1 ? b.y : comp == 2 ? b.z :
                  comp == 3 ? b.w : ssc[j];
        }
        o[t] = val;
    }
}

// ---- calibration: 28672 dependent v_fma_f32 (~115K cycles of known work).
// dur_us of this dispatch reveals the effective shader clock:
// ~48us -> 2.4GHz; ~95us -> 1.2GHz; ~190us -> 0.6GHz. Removed next round.
__global__ __launch_bounds__(64) void calib_kernel(float* ws)
{
    float x = 1.0f + (float)threadIdx.x * 1e-7f;
    float m = 0.9999999f, a = 1e-9f;
    #pragma unroll 1
    for (int i = 0; i < 1792; ++i) {
        #pragma unroll
        for (int k = 0; k < 16; ++k)
            asm volatile("v_fma_f32 %0, %0, %1, %2" : "+v"(x) : "v"(m), "v"(a));
    }
    ws[threadIdx.x] = x;   // keep alive; d_ws is scratch, never validated
}

extern "C" void kernel_launch(void* const* d_in, const int* in_sizes, int n_in,
                              void* d_out, int out_size, void* d_ws, size_t ws_size,
                              hipStream_t stream) {
    const float* rois      = (const float*)d_in[0];
    const float* cls_prob  = (const float*)d_in[1];
    const float* bbox_pred = (const float*)d_in[2];
    const float* im_info   = (const float*)d_in[3];
    const float* gt        = (const float*)d_in[4];
    const int*   nb        = (const int*)d_in[5];
    float* out = (float*)d_out;

    detect_kernel<<<dim3(N_CLS_OUT), dim3(NT), 0, stream>>>(
        rois, cls_prob, bbox_pred, im_info, gt, nb, out);
    calib_kernel<<<dim3(1), dim3(64), 0, stream>>>((float*)d_ws);
}

// Round 9
// 37.239 us; speedup vs baseline: 4.1431x; 4.1431x over previous
//
#include <hip/hip_runtime.h>

typedef unsigned long long u64;

#define N_ROIS 2048
#define N_CLSX 21
#define N_CLS_OUT 20
#define SCORE_T 0.3f
#define NMS_T 0.3f
#define DEDUP_T 0.3f
#define NT 256
#define NWAVES (NT / 64)
#define CPW (N_ROIS / 64 / NWAVES)   // 8 chunks of 64 rois per wave
#define NFAST 128                    // register-path bound (2 slots/lane)
#define TB 8                         // transpose blocks in prep
#define ZB 56                        // zero-fill blocks in prep

__device__ __forceinline__ float iou_f(float ax1, float ay1, float ax2, float ay2,
                                       float aarea,
                                       float bx1, float by1, float bx2, float by2,
                                       float barea) {
    float ix1 = fmaxf(ax1, bx1), iy1 = fmaxf(ay1, by1);
    float ix2 = fminf(ax2, bx2), iy2 = fminf(ay2, by2);
    float iw = fmaxf(ix2 - ix1, 0.0f), ih = fmaxf(iy2 - iy1, 0.0f);
    float inter = iw * ih;
    return inter / (aarea + barea - inter + 1e-6f);
}

// ============ K0: transpose scores into ws + zero-fill output ============
__global__ __launch_bounds__(256) void prep_kernel(
    const float* __restrict__ cls_prob,  // (2048,21)
    float* __restrict__ scT,             // ws: [20][2048]
    float* __restrict__ out)             // (20,2048,5)
{
    const int tid = threadIdx.x;
    const int bx = blockIdx.x;
    if (bx < TB) {
        __shared__ float lsc[256][22];   // pad 21->22 (2-way conflict: free)
        const int roi0 = bx * 256;
        for (int t = tid; t < 256 * N_CLSX; t += 256) {
            int r = t / N_CLSX, c = t - r * N_CLSX;
            lsc[r][c] = cls_prob[roi0 * N_CLSX + t];
        }
        __syncthreads();
        // per iter: all 256 lanes write consecutive addresses (coalesced)
        for (int cseg = 0; cseg < N_CLS_OUT; ++cseg)
            scT[cseg * N_ROIS + roi0 + tid] = lsc[tid][cseg + 1];
    } else {
        float4* o4 = (float4*)out;
        const int total = N_CLS_OUT * N_ROIS * 5 / 4;  // 51200
        float4 z = make_float4(0.f, 0.f, 0.f, 0.f);
        for (int t = (bx - TB) * 256 + tid; t < total; t += ZB * 256)
            o4[t] = z;
    }
}

// ============ K1: per-class compact + rank + NMS + dedup + kept-row write ====
__global__ __launch_bounds__(NT) void detect_kernel(
    const float* __restrict__ rois,      // (2048,5)
    const float* __restrict__ scT,       // ws: [20][2048]
    const float* __restrict__ bbox_pred, // (2048,84)
    const float* __restrict__ im_info,   // (3,)
    const float* __restrict__ gt_boxes,  // (50,5)
    const int*   __restrict__ num_boxes,
    float* __restrict__ out)             // (20,2048,5) — pre-zeroed by K0
{
    __shared__ float  vsc[N_ROIS];
    __shared__ int    vidx[N_ROIS];
    __shared__ float4 sbox[N_ROIS];
    __shared__ float  ssc[N_ROIS];
    __shared__ unsigned char keepb[N_ROIS];    // fallback only
    __shared__ float4 sgt[64];
    __shared__ int    wbase[NWAVES];
    __shared__ u64    kwords[2];
    __shared__ u64    dupw[2];

    const int tid = threadIdx.x;
    const int wid = tid >> 6, lane = tid & 63;
    const int cseg = blockIdx.x;          // 0..19, class = cseg+1
    const int cls = cseg + 1;
    const int ng = *num_boxes;
    const float W = im_info[1], H = im_info[0];
    float* o = out + (size_t)cseg * N_ROIS * 5;
    const float* myscores = scT + cseg * N_ROIS;   // contiguous 8KB

    // ---- phase 1: compact from contiguous scores (coalesced loads)
    u64 masks[CPW];
    float vals[CPW];
    int mycnt = 0;
    #pragma unroll
    for (int c = 0; c < CPW; ++c) {
        int i = ((wid * CPW + c) << 6) + lane;
        float sc = myscores[i];
        vals[c] = sc;
        masks[c] = __ballot(sc > SCORE_T);
        mycnt += __popcll(masks[c]);
    }
    if (lane == 0) wbase[wid] = mycnt;
    __syncthreads();                               // B1
    int base = 0;
    for (int w = 0; w < wid; ++w) base += wbase[w];
    int nvtot = 0;
    for (int w = 0; w < NWAVES; ++w) nvtot += wbase[w];
    const int nv = nvtot;
    #pragma unroll
    for (int c = 0; c < CPW; ++c) {
        int i = ((wid * CPW + c) << 6) + lane;
        u64 m = masks[c];
        if ((m >> lane) & 1ULL) {
            int pre = __popcll(m & ((1ULL << lane) - 1ULL));
            vidx[base + pre] = i;
            vsc[base + pre]  = vals[c];
        }
        base += __popcll(m);
    }
    __syncthreads();                               // B2

    if (nv <= NFAST) {
        // ================= FAST PATH: one-wave register NMS =================
        if (wid == 0) {
            // lane owns compact slots (lane) and (64+lane)
            float s0 = (lane < nv)      ? vsc[lane]      : 0.0f;
            float s1 = (64 + lane < nv) ? vsc[64 + lane] : 0.0f;
            int  idx0 = (lane < nv)      ? vidx[lane]      : 0;
            int  idx1 = (64 + lane < nv) ? vidx[64 + lane] : 0;

            // issue decode gathers NOW; the rank loop below hides the latency
            float ax1 = rois[idx0 * 5 + 1], ay1 = rois[idx0 * 5 + 2];
            float ax2 = rois[idx0 * 5 + 3], ay2 = rois[idx0 * 5 + 4];
            const float* dpa = &bbox_pred[idx0 * 84 + cls * 4];
            float da0 = dpa[0], da1 = dpa[1], da2 = dpa[2], da3 = dpa[3];
            float bx1v = rois[idx1 * 5 + 1], by1v = rois[idx1 * 5 + 2];
            float bx2v = rois[idx1 * 5 + 3], by2v = rois[idx1 * 5 + 4];
            const float* dpb = &bbox_pred[idx1 * 84 + cls * 4];
            float db0 = dpb[0], db1 = dpb[1], db2 = dpb[2], db3 = dpb[3];

            // rank via shfl count-loop (no memory)
            int r0 = 0, r1 = 0;
            const int n0 = nv < 64 ? nv : 64;
            for (int u = 0; u < n0; ++u) {
                float su0 = __shfl(s0, u);
                float su1 = __shfl(s1, u);
                r0 += (su0 > s0) || (su0 == s0 && u < lane);
                r1 += (su0 > s1) || (su0 == s1);
                if (64 + u < nv) {
                    r0 += (su1 > s0);
                    r1 += (su1 > s1) || (su1 == s1 && u < lane);
                }
            }

            // finish decode (loads have been in flight across the rank loop)
            #define DECODE2(X1,Y1,X2,Y2,D0,D1,D2,D3,B)                       \
            {                                                                \
                float w = (X2) - (X1) + 1.0f, h = (Y2) - (Y1) + 1.0f;        \
                float cx = (X1) + 0.5f * w, cy = (Y1) + 0.5f * h;            \
                float pcx = (D0) * 0.1f * w + cx, pcy = (D1) * 0.1f * h + cy;\
                float pw = expf((D2) * 0.2f) * w, ph = expf((D3) * 0.2f) * h;\
                B.x = fminf(fmaxf(pcx - 0.5f * pw, 0.0f), W - 1.0f);         \
                B.y = fminf(fmaxf(pcy - 0.5f * ph, 0.0f), H - 1.0f);         \
                B.z = fminf(fmaxf(pcx + 0.5f * pw, 0.0f), W - 1.0f);         \
                B.w = fminf(fmaxf(pcy + 0.5f * ph, 0.0f), H - 1.0f);         \
            }
            float4 c0, c1;
            DECODE2(ax1, ay1, ax2, ay2, da0, da1, da2, da3, c0)
            DECODE2(bx1v, by1v, bx2v, by2v, db0, db1, db2, db3, c1)

            // scatter to ranked position (LDS = the permutation network)
            if (lane < nv)      { sbox[r0] = c0; ssc[r0] = s0; }
            if (64 + lane < nv) { sbox[r1] = c1; ssc[r1] = s1; }
        } else if (wid == 3) {
            for (int g = lane; g < ng; g += 64)
                sgt[g] = make_float4(gt_boxes[g * 5 + 0], gt_boxes[g * 5 + 1],
                                     gt_boxes[g * 5 + 2], gt_boxes[g * 5 + 3]);
        }
        __syncthreads();                             // B3 (sbox/sgt ready)

        if (wid == 0) {
            // read back in ranked order (one ds_read_b128 per slot)
            float4 b0 = (lane < nv)      ? sbox[lane]      : make_float4(0,0,0,0);
            float4 b1 = (64 + lane < nv) ? sbox[64 + lane] : make_float4(0,0,0,0);
            float ar0 = (b0.z - b0.x) * (b0.w - b0.y);
            float ar1 = (b1.z - b1.x) * (b1.w - b1.y);
            u64 S0lo = 0, S0hi = 0, S1lo = 0, S1hi = 0;
            for (int i = 0; i < nv; ++i) {
                bool hi = i >= 64;
                int src = i & 63;
                float cx1 = __shfl(hi ? b1.x : b0.x, src);
                float cy1 = __shfl(hi ? b1.y : b0.y, src);
                float cx2 = __shfl(hi ? b1.z : b0.z, src);
                float cy2 = __shfl(hi ? b1.w : b0.w, src);
                float car = __shfl(hi ? ar1 : ar0, src);
                float i0 = iou_f(cx1, cy1, cx2, cy2, car, b0.x, b0.y, b0.z, b0.w, ar0);
                float i1 = iou_f(cx1, cy1, cx2, cy2, car, b1.x, b1.y, b1.z, b1.w, ar1);
                bool sup0 = (i0 > NMS_T) && (i < lane);        // rank(slot0)=lane
                bool sup1 = (i1 > NMS_T) && (i < 64 + lane);   // rank(slot1)=64+lane
                if (i < 64) {
                    S0lo |= sup0 ? (1ULL << i) : 0ULL;
                    S1lo |= sup1 ? (1ULL << i) : 0ULL;
                } else {
                    S0hi |= sup0 ? (1ULL << (i - 64)) : 0ULL;
                    S1hi |= sup1 ? (1ULL << (i - 64)) : 0ULL;
                }
            }
            // Jacobi forward-substitution to the unique greedy fixpoint
            bool init0 = lane < nv, init1 = 64 + lane < nv;
            u64 kw0 = __ballot(init0), kw1 = __ballot(init1);
            for (int it = 0; it < NFAST; ++it) {
                bool a0 = init0 && !((S0lo & kw0) | (S0hi & kw1));
                bool a1 = init1 && !((S1lo & kw0) | (S1hi & kw1));
                u64 nk0 = __ballot(a0), nk1 = __ballot(a1);
                bool done = (nk0 == kw0) && (nk1 == kw1);
                kw0 = nk0; kw1 = nk1;
                if (done) break;
            }
            if (lane == 0) { kwords[0] = kw0; kwords[1] = kw1; }
        } else if (wid == 1 || wid == 2) {
            // GT dedup in parallel (ranks 0-63 on wave1, 64-127 on wave2)
            int e = (wid - 1) * 64 + lane;
            bool dup = false;
            if (e < nv) {
                float4 a = sbox[e];
                float aarea = (a.z - a.x) * (a.w - a.y);
                for (int g = 0; g < ng; ++g) {
                    float4 gb = sgt[g];
                    float garea = (gb.z - gb.x) * (gb.w - gb.y);
                    dup |= iou_f(a.x, a.y, a.z, a.w, aarea,
                                 gb.x, gb.y, gb.z, gb.w, garea) > DEDUP_T;
                }
            }
            u64 wd = __ballot(dup);
            if (lane == 0) dupw[wid - 1] = wd;
        }
        __syncthreads();                             // B4

        // kept-row write only (output pre-zeroed by prep_kernel)
        if (tid < NFAST && tid < nv) {
            bool kept = ((kwords[tid >> 6] >> (tid & 63)) & 1ULL) &&
                        !((dupw[tid >> 6] >> (tid & 63)) & 1ULL);
            if (kept) {
                float4 b = sbox[tid];
                float s = ssc[tid];
                float* orow = o + tid * 5;
                orow[0] = b.x; orow[1] = b.y; orow[2] = b.z; orow[3] = b.w;
                orow[4] = s;
            }
        }
        return;
    }

    // ========== FALLBACK (nv > 128): barrier-per-row greedy ==========
    for (int g = tid; g < ng; g += NT)
        sgt[g] = make_float4(gt_boxes[g * 5 + 0], gt_boxes[g * 5 + 1],
                             gt_boxes[g * 5 + 2], gt_boxes[g * 5 + 3]);

    for (int v = tid; v < nv; v += NT) {
        int idx = vidx[v];
        float x1 = rois[idx * 5 + 1], y1 = rois[idx * 5 + 2];
        float x2 = rois[idx * 5 + 3], y2 = rois[idx * 5 + 4];
        const float* dp = &bbox_pred[idx * 84 + cls * 4];
        float d0 = dp[0], d1 = dp[1], d2 = dp[2], d3 = dp[3];
        float sc = vsc[v];
        int r = 0;
        for (int u = 0; u < nv; ++u) {
            float su = vsc[u];
            r += (su > sc) || (su == sc && u < v);
        }
        float w = x2 - x1 + 1.0f, h = y2 - y1 + 1.0f;
        float cx = x1 + 0.5f * w, cy = y1 + 0.5f * h;
        float pcx = d0 * 0.1f * w + cx, pcy = d1 * 0.1f * h + cy;
        float pw = expf(d2 * 0.2f) * w, ph = expf(d3 * 0.2f) * h;
        float4 b;
        b.x = fminf(fmaxf(pcx - 0.5f * pw, 0.0f), W - 1.0f);
        b.y = fminf(fmaxf(pcy - 0.5f * ph, 0.0f), H - 1.0f);
        b.z = fminf(fmaxf(pcx + 0.5f * pw, 0.0f), W - 1.0f);
        b.w = fminf(fmaxf(pcy + 0.5f * ph, 0.0f), H - 1.0f);
        sbox[r] = b;
        ssc[r]  = sc;
        keepb[r] = 1;
    }
    __syncthreads();

    for (int i = 0; i < nv; ++i) {
        __syncthreads();
        if (keepb[i]) {
            float4 a = sbox[i];
            float aarea = (a.z - a.x) * (a.w - a.y);
            for (int j = i + 1 + tid; j < nv; j += NT) {
                if (keepb[j]) {
                    float4 bb = sbox[j];
                    float barea = (bb.z - bb.x) * (bb.w - bb.y);
                    if (iou_f(a.x, a.y, a.z, a.w, aarea,
                              bb.x, bb.y, bb.z, bb.w, barea) > NMS_T)
                        keepb[j] = 0;
                }
            }
        }
    }
    __syncthreads();
    for (int v = tid; v < nv; v += NT) {
        bool kept = keepb[v] != 0;
        if (kept) {
            float4 a = sbox[v];
            float aarea = (a.z - a.x) * (a.w - a.y);
            for (int g = 0; g < ng; ++g) {
                float4 gb = sgt[g];
                float garea = (gb.z - gb.x) * (gb.w - gb.y);
                kept = kept && !(iou_f(a.x, a.y, a.z, a.w, aarea,
                                       gb.x, gb.y, gb.z, gb.w, garea) > DEDUP_T);
            }
        }
        if (kept) {
            float4 b = sbox[v];
            float* orow = o + v * 5;
            orow[0] = b.x; orow[1] = b.y; orow[2] = b.z; orow[3] = b.w;
            orow[4] = ssc[v];
        }
    }
}

extern "C" void kernel_launch(void* const* d_in, const int* in_sizes, int n_in,
                              void* d_out, int out_size, void* d_ws, size_t ws_size,
                              hipStream_t stream) {
    const float* rois      = (const float*)d_in[0];
    const float* cls_prob  = (const float*)d_in[1];
    const float* bbox_pred = (const float*)d_in[2];
    const float* im_info   = (const float*)d_in[3];
    const float* gt        = (const float*)d_in[4];
    const int*   nb        = (const int*)d_in[5];
    float* out = (float*)d_out;
    float* scT = (float*)d_ws;

    prep_kernel<<<dim3(TB + ZB), dim3(256), 0, stream>>>(cls_prob, scT, out);
    detect_kernel<<<dim3(N_CLS_OUT), dim3(NT), 0, stream>>>(
        rois, scT, bbox_pred, im_info, gt, nb, out);
}

// Round 10
// 32.504 us; speedup vs baseline: 4.7467x; 1.1457x over previous
//
#include <hip/hip_runtime.h>

typedef unsigned long long u64;

#define N_ROIS 2048
#define N_CLSX 21
#define N_CLS_OUT 20
#define SCORE_T 0.3f
#define NMS_T 0.3f
#define DEDUP_T 0.3f
#define NT 256
#define NWAVES (NT / 64)
#define CPW (N_ROIS / 64 / NWAVES)   // 8 chunks of 64 rois per wave
#define NFAST 128                    // register-path bound (2 slots/lane)

__device__ __forceinline__ float iou_f(float ax1, float ay1, float ax2, float ay2,
                                       float aarea,
                                       float bx1, float by1, float bx2, float by2,
                                       float barea) {
    float ix1 = fmaxf(ax1, bx1), iy1 = fmaxf(ay1, by1);
    float ix2 = fminf(ax2, bx2), iy2 = fminf(ay2, by2);
    float iw = fmaxf(ix2 - ix1, 0.0f), ih = fmaxf(iy2 - iy1, 0.0f);
    float inter = iw * ih;
    return inter / (aarea + barea - inter + 1e-6f);
}

__global__ __launch_bounds__(NT) void detect_kernel(
    const float* __restrict__ rois,      // (2048,5)
    const float* __restrict__ cls_prob,  // (2048,21)
    const float* __restrict__ bbox_pred, // (2048,84)
    const float* __restrict__ im_info,   // (3,)
    const float* __restrict__ gt_boxes,  // (50,5)
    const int*   __restrict__ num_boxes,
    float* __restrict__ out)             // (20,2048,5)
{
    __shared__ float  vsc[N_ROIS];
    __shared__ int    vidx[N_ROIS];
    __shared__ float4 sbox[N_ROIS];
    __shared__ float  ssc[N_ROIS];
    __shared__ unsigned char keepb[N_ROIS];    // fallback only
    __shared__ float4 sgt[64];
    __shared__ int    wbase[NWAVES];
    __shared__ u64    kwords[2];
    __shared__ u64    dupw[2];

    const int tid = threadIdx.x;
    const int wid = tid >> 6, lane = tid & 63;
    const int cls = blockIdx.x + 1;
    const int ng = *num_boxes;
    const float W = im_info[1], H = im_info[0];
    float* o = out + (size_t)blockIdx.x * N_ROIS * 5;

    // ---- phase 1: compact straight from global (8 independent strided loads;
    // every 128B line is used by other lanes -> L1/L2 resident across blocks)
    u64 masks[CPW];
    float vals[CPW];
    int mycnt = 0;
    #pragma unroll
    for (int c = 0; c < CPW; ++c) {
        int i = ((wid * CPW + c) << 6) + lane;
        float sc = cls_prob[i * N_CLSX + cls];
        vals[c] = sc;
        masks[c] = __ballot(sc > SCORE_T);
        mycnt += __popcll(masks[c]);
    }
    if (lane == 0) wbase[wid] = mycnt;
    __syncthreads();                               // B1
    int base = 0;
    for (int w = 0; w < wid; ++w) base += wbase[w];
    int nvtot = 0;
    for (int w = 0; w < NWAVES; ++w) nvtot += wbase[w];
    const int nv = nvtot;
    #pragma unroll
    for (int c = 0; c < CPW; ++c) {
        int i = ((wid * CPW + c) << 6) + lane;
        u64 m = masks[c];
        if ((m >> lane) & 1ULL) {
            int pre = __popcll(m & ((1ULL << lane) - 1ULL));
            vidx[base + pre] = i;
            vsc[base + pre]  = vals[c];
        }
        base += __popcll(m);
    }
    __syncthreads();                               // B2

    if (nv <= NFAST) {
        // ================= FAST PATH: one-wave register NMS =================
        if (wid == 0) {
            // lane owns compact slots (lane) and (64+lane)
            float s0 = (lane < nv)      ? vsc[lane]      : 0.0f;
            float s1 = (64 + lane < nv) ? vsc[64 + lane] : 0.0f;
            int  idx0 = (lane < nv)      ? vidx[lane]      : 0;
            int  idx1 = (64 + lane < nv) ? vidx[64 + lane] : 0;

            // issue decode gathers NOW; the rank loop below hides the latency
            float ax1 = rois[idx0 * 5 + 1], ay1 = rois[idx0 * 5 + 2];
            float ax2 = rois[idx0 * 5 + 3], ay2 = rois[idx0 * 5 + 4];
            const float* dpa = &bbox_pred[idx0 * 84 + cls * 4];
            float da0 = dpa[0], da1 = dpa[1], da2 = dpa[2], da3 = dpa[3];
            float bx1v = rois[idx1 * 5 + 1], by1v = rois[idx1 * 5 + 2];
            float bx2v = rois[idx1 * 5 + 3], by2v = rois[idx1 * 5 + 4];
            const float* dpb = &bbox_pred[idx1 * 84 + cls * 4];
            float db0 = dpb[0], db1 = dpb[1], db2 = dpb[2], db3 = dpb[3];

            // rank via shfl count-loop (no memory)
            int r0 = 0, r1 = 0;
            const int n0 = nv < 64 ? nv : 64;
            for (int u = 0; u < n0; ++u) {
                float su0 = __shfl(s0, u);
                float su1 = __shfl(s1, u);
                r0 += (su0 > s0) || (su0 == s0 && u < lane);
                r1 += (su0 > s1) || (su0 == s1);
                if (64 + u < nv) {
                    r0 += (su1 > s0);
                    r1 += (su1 > s1) || (su1 == s1 && u < lane);
                }
            }

            // finish decode (loads have been in flight across the rank loop)
            #define DECODE2(X1,Y1,X2,Y2,D0,D1,D2,D3,B)                       \
            {                                                                \
                float w = (X2) - (X1) + 1.0f, h = (Y2) - (Y1) + 1.0f;        \
                float cx = (X1) + 0.5f * w, cy = (Y1) + 0.5f * h;            \
                float pcx = (D0) * 0.1f * w + cx, pcy = (D1) * 0.1f * h + cy;\
                float pw = expf((D2) * 0.2f) * w, ph = expf((D3) * 0.2f) * h;\
                B.x = fminf(fmaxf(pcx - 0.5f * pw, 0.0f), W - 1.0f);         \
                B.y = fminf(fmaxf(pcy - 0.5f * ph, 0.0f), H - 1.0f);         \
                B.z = fminf(fmaxf(pcx + 0.5f * pw, 0.0f), W - 1.0f);         \
                B.w = fminf(fmaxf(pcy + 0.5f * ph, 0.0f), H - 1.0f);         \
            }
            float4 c0, c1;
            DECODE2(ax1, ay1, ax2, ay2, da0, da1, da2, da3, c0)
            DECODE2(bx1v, by1v, bx2v, by2v, db0, db1, db2, db3, c1)

            // scatter to ranked position (LDS = the permutation network)
            if (lane < nv)      { sbox[r0] = c0; ssc[r0] = s0; }
            if (64 + lane < nv) { sbox[r1] = c1; ssc[r1] = s1; }
        } else {
            // waves 1-3: stage gt + zero-fill this class's output (overlaps
            // wave0's rank/decode; same-address order preserved by barriers)
            if (wid == 3)
                for (int g = lane; g < ng; g += 64)
                    sgt[g] = make_float4(gt_boxes[g * 5 + 0], gt_boxes[g * 5 + 1],
                                         gt_boxes[g * 5 + 2], gt_boxes[g * 5 + 3]);
            float4* o4 = (float4*)o;                 // 2560 float4 per class
            float4 z4 = make_float4(0.f, 0.f, 0.f, 0.f);
            for (int t = (wid - 1) * 64 + lane; t < N_ROIS * 5 / 4; t += 192)
                o4[t] = z4;
        }
        __syncthreads();                             // B3 (sbox/sgt/zeros ready)

        if (wid == 0) {
            // read back in ranked order (one ds_read_b128 per slot)
            float4 b0 = (lane < nv)      ? sbox[lane]      : make_float4(0,0,0,0);
            float4 b1 = (64 + lane < nv) ? sbox[64 + lane] : make_float4(0,0,0,0);
            float ar0 = (b0.z - b0.x) * (b0.w - b0.y);
            float ar1 = (b1.z - b1.x) * (b1.w - b1.y);
            u64 S0lo = 0, S0hi = 0, S1lo = 0, S1hi = 0;
            for (int i = 0; i < nv; ++i) {
                bool hi = i >= 64;
                int src = i & 63;
                float cx1 = __shfl(hi ? b1.x : b0.x, src);
                float cy1 = __shfl(hi ? b1.y : b0.y, src);
                float cx2 = __shfl(hi ? b1.z : b0.z, src);
                float cy2 = __shfl(hi ? b1.w : b0.w, src);
                float car = __shfl(hi ? ar1 : ar0, src);
                float i0 = iou_f(cx1, cy1, cx2, cy2, car, b0.x, b0.y, b0.z, b0.w, ar0);
                float i1 = iou_f(cx1, cy1, cx2, cy2, car, b1.x, b1.y, b1.z, b1.w, ar1);
                bool sup0 = (i0 > NMS_T) && (i < lane);        // rank(slot0)=lane
                bool sup1 = (i1 > NMS_T) && (i < 64 + lane);   // rank(slot1)=64+lane
                if (i < 64) {
                    S0lo |= sup0 ? (1ULL << i) : 0ULL;
                    S1lo |= sup1 ? (1ULL << i) : 0ULL;
                } else {
                    S0hi |= sup0 ? (1ULL << (i - 64)) : 0ULL;
                    S1hi |= sup1 ? (1ULL << (i - 64)) : 0ULL;
                }
            }
            // Jacobi forward-substitution to the unique greedy fixpoint
            bool init0 = lane < nv, init1 = 64 + lane < nv;
            u64 kw0 = __ballot(init0), kw1 = __ballot(init1);
            for (int it = 0; it < NFAST; ++it) {
                bool a0 = init0 && !((S0lo & kw0) | (S0hi & kw1));
                bool a1 = init1 && !((S1lo & kw0) | (S1hi & kw1));
                u64 nk0 = __ballot(a0), nk1 = __ballot(a1);
                bool done = (nk0 == kw0) && (nk1 == kw1);
                kw0 = nk0; kw1 = nk1;
                if (done) break;
            }
            if (lane == 0) { kwords[0] = kw0; kwords[1] = kw1; }
        } else if (wid == 1 || wid == 2) {
            // GT dedup in parallel (ranks 0-63 on wave1, 64-127 on wave2)
            int e = (wid - 1) * 64 + lane;
            bool dup = false;
            if (e < nv) {
                float4 a = sbox[e];
                float aarea = (a.z - a.x) * (a.w - a.y);
                for (int g = 0; g < ng; ++g) {
                    float4 gb = sgt[g];
                    float garea = (gb.z - gb.x) * (gb.w - gb.y);
                    dup |= iou_f(a.x, a.y, a.z, a.w, aarea,
                                 gb.x, gb.y, gb.z, gb.w, garea) > DEDUP_T;
                }
            }
            u64 wd = __ballot(dup);
            if (lane == 0) dupw[wid - 1] = wd;
        }
        __syncthreads();                             // B4

        // kept-row write only (zeros already laid down by waves 1-3)
        if (tid < NFAST && tid < nv) {
            bool kept = ((kwords[tid >> 6] >> (tid & 63)) & 1ULL) &&
                        !((dupw[tid >> 6] >> (tid & 63)) & 1ULL);
            if (kept) {
                float4 b = sbox[tid];
                float s = ssc[tid];
                float* orow = o + tid * 5;
                orow[0] = b.x; orow[1] = b.y; orow[2] = b.z; orow[3] = b.w;
                orow[4] = s;
            }
        }
        return;
    }

    // ========== FALLBACK (nv > 128): barrier-per-row greedy, full write ==========
    for (int g = tid; g < ng; g += NT)
        sgt[g] = make_float4(gt_boxes[g * 5 + 0], gt_boxes[g * 5 + 1],
                             gt_boxes[g * 5 + 2], gt_boxes[g * 5 + 3]);

    for (int v = tid; v < nv; v += NT) {
        int idx = vidx[v];
        float x1 = rois[idx * 5 + 1], y1 = rois[idx * 5 + 2];
        float x2 = rois[idx * 5 + 3], y2 = rois[idx * 5 + 4];
        const float* dp = &bbox_pred[idx * 84 + cls * 4];
        float d0 = dp[0], d1 = dp[1], d2 = dp[2], d3 = dp[3];
        float sc = vsc[v];
        int r = 0;
        for (int u = 0; u < nv; ++u) {
            float su = vsc[u];
            r += (su > sc) || (su == sc && u < v);
        }
        float w = x2 - x1 + 1.0f, h = y2 - y1 + 1.0f;
        float cx = x1 + 0.5f * w, cy = y1 + 0.5f * h;
        float pcx = d0 * 0.1f * w + cx, pcy = d1 * 0.1f * h + cy;
        float pw = expf(d2 * 0.2f) * w, ph = expf(d3 * 0.2f) * h;
        float4 b;
        b.x = fminf(fmaxf(pcx - 0.5f * pw, 0.0f), W - 1.0f);
        b.y = fminf(fmaxf(pcy - 0.5f * ph, 0.0f), H - 1.0f);
        b.z = fminf(fmaxf(pcx + 0.5f * pw, 0.0f), W - 1.0f);
        b.w = fminf(fmaxf(pcy + 0.5f * ph, 0.0f), H - 1.0f);
        sbox[r] = b;
        ssc[r]  = sc;
        keepb[r] = 1;
    }
    __syncthreads();

    for (int i = 0; i < nv; ++i) {
        __syncthreads();
        if (keepb[i]) {
            float4 a = sbox[i];
            float aarea = (a.z - a.x) * (a.w - a.y);
            for (int j = i + 1 + tid; j < nv; j += NT) {
                if (keepb[j]) {
                    float4 bb = sbox[j];
                    float barea = (bb.z - bb.x) * (bb.w - bb.y);
                    if (iou_f(a.x, a.y, a.z, a.w, aarea,
                              bb.x, bb.y, bb.z, bb.w, barea) > NMS_T)
                        keepb[j] = 0;
                }
            }
        }
    }
    __syncthreads();
    for (int v = tid; v < nv; v += NT) {
        if (keepb[v]) {
            float4 a = sbox[v];
            float aarea = (a.z - a.x) * (a.w - a.y);
            bool dup = false;
            for (int g = 0; g < ng; ++g) {
                float4 gb = sgt[g];
                float garea = (gb.z - gb.x) * (gb.w - gb.y);
                dup |= iou_f(a.x, a.y, a.z, a.w, aarea,
                             gb.x, gb.y, gb.z, gb.w, garea) > DEDUP_T;
            }
            if (dup) keepb[v] = 0;
        }
    }
    __syncthreads();
    for (int t = tid; t < N_ROIS * 5; t += NT) {
        int j = t / 5, comp = t - 5 * j;
        float val = 0.0f;
        if (j < nv && keepb[j]) {
            float4 b = sbox[j];
            val = comp == 0 ? b.x : comp == 1 ? b.y : comp == 2 ? b.z :
                  comp == 3 ? b.w : ssc[j];
        }
        o[t] = val;
    }
}

extern "C" void kernel_launch(void* const* d_in, const int* in_sizes, int n_in,
                              void* d_out, int out_size, void* d_ws, size_t ws_size,
                              hipStream_t stream) {
    const float* rois      = (const float*)d_in[0];
    const float* cls_prob  = (const float*)d_in[1];
    const float* bbox_pred = (const float*)d_in[2];
    const float* im_info   = (const float*)d_in[3];
    const float* gt        = (const float*)d_in[4];
    const int*   nb        = (const int*)d_in[5];
    float* out = (float*)d_out;

    detect_kernel<<<dim3(N_CLS_OUT), dim3(NT), 0, stream>>>(
        rois, cls_prob, bbox_pred, im_info, gt, nb, out);
}

// Round 11
// 30.966 us; speedup vs baseline: 4.9823x; 1.0497x over previous
//
#include <hip/hip_runtime.h>

typedef unsigned long long u64;

#define N_ROIS 2048
#define N_CLSX 21
#define N_CLS_OUT 20
#define SCORE_T 0.3f
#define NMS_T 0.3f
#define DEDUP_T 0.3f
#define NT 256
#define NWAVES (NT / 64)
#define CPW (N_ROIS / 64 / NWAVES)   // 8 chunks of 64 rois per wave
#define NFAST 128                    // register-path bound (2 slots/lane)

__device__ __forceinline__ float iou_f(float ax1, float ay1, float ax2, float ay2,
                                       float aarea,
                                       float bx1, float by1, float bx2, float by2,
                                       float barea) {
    float ix1 = fmaxf(ax1, bx1), iy1 = fmaxf(ay1, by1);
    float ix2 = fminf(ax2, bx2), iy2 = fminf(ay2, by2);
    float iw = fmaxf(ix2 - ix1, 0.0f), ih = fmaxf(iy2 - iy1, 0.0f);
    float inter = iw * ih;
    return inter / (aarea + barea - inter + 1e-6f);
}

// decode a single (roi idx, cls) box into a clipped float4
#define DECODE_IDX(IDX, B)                                                    \
{                                                                             \
    float x1 = rois[(IDX) * 5 + 1], y1 = rois[(IDX) * 5 + 2];                 \
    float x2 = rois[(IDX) * 5 + 3], y2 = rois[(IDX) * 5 + 4];                 \
    const float* dp = &bbox_pred[(IDX) * 84 + cls * 4];                       \
    float d0 = dp[0], d1 = dp[1], d2 = dp[2], d3 = dp[3];                     \
    float w = x2 - x1 + 1.0f, h = y2 - y1 + 1.0f;                             \
    float cx = x1 + 0.5f * w, cy = y1 + 0.5f * h;                             \
    float pcx = d0 * 0.1f * w + cx, pcy = d1 * 0.1f * h + cy;                 \
    float pw = expf(d2 * 0.2f) * w, ph = expf(d3 * 0.2f) * h;                 \
    B.x = fminf(fmaxf(pcx - 0.5f * pw, 0.0f), W - 1.0f);                      \
    B.y = fminf(fmaxf(pcy - 0.5f * ph, 0.0f), H - 1.0f);                      \
    B.z = fminf(fmaxf(pcx + 0.5f * pw, 0.0f), W - 1.0f);                      \
    B.w = fminf(fmaxf(pcy + 0.5f * ph, 0.0f), H - 1.0f);                      \
}

__global__ __launch_bounds__(NT) void detect_kernel(
    const float* __restrict__ rois,      // (2048,5)
    const float* __restrict__ cls_prob,  // (2048,21)
    const float* __restrict__ bbox_pred, // (2048,84)
    const float* __restrict__ im_info,   // (3,)
    const float* __restrict__ gt_boxes,  // (50,5)
    const int*   __restrict__ num_boxes,
    float* __restrict__ out)             // (20,2048,5)
{
    __shared__ float  vsc[N_ROIS];
    __shared__ int    vidx[N_ROIS];
    __shared__ float4 sbox[N_ROIS];            // fallback only
    __shared__ float  ssc[N_ROIS];             // fallback only
    __shared__ unsigned char keepb[N_ROIS];    // fallback only
    __shared__ float4 sgt[64];
    __shared__ int    wbase[NWAVES];
    __shared__ int    rrank[NFAST];
    __shared__ u64    dupw[2];

    const int tid = threadIdx.x;
    const int wid = tid >> 6, lane = tid & 63;
    const int cls = blockIdx.x + 1;
    const int ng = *num_boxes;
    const float W = im_info[1], H = im_info[0];
    float* o = out + (size_t)blockIdx.x * N_ROIS * 5;

    // ---- phase 1: compact straight from global (independent strided loads)
    u64 masks[CPW];
    float vals[CPW];
    int mycnt = 0;
    #pragma unroll
    for (int c = 0; c < CPW; ++c) {
        int i = ((wid * CPW + c) << 6) + lane;
        float sc = cls_prob[i * N_CLSX + cls];
        vals[c] = sc;
        masks[c] = __ballot(sc > SCORE_T);
        mycnt += __popcll(masks[c]);
    }
    if (lane == 0) wbase[wid] = mycnt;
    __syncthreads();                               // B1
    int base = 0;
    for (int w = 0; w < wid; ++w) base += wbase[w];
    int nvtot = 0;
    for (int w = 0; w < NWAVES; ++w) nvtot += wbase[w];
    const int nv = nvtot;
    #pragma unroll
    for (int c = 0; c < CPW; ++c) {
        int i = ((wid * CPW + c) << 6) + lane;
        u64 m = masks[c];
        if ((m >> lane) & 1ULL) {
            int pre = __popcll(m & ((1ULL << lane) - 1ULL));
            vidx[base + pre] = i;
            vsc[base + pre]  = vals[c];
        }
        base += __popcll(m);
    }
    if (wid == 3)   // gt staging, consumed by waves 1/2 after B2
        for (int g = lane; g < ng; g += 64)
            sgt[g] = make_float4(gt_boxes[g * 5 + 0], gt_boxes[g * 5 + 1],
                                 gt_boxes[g * 5 + 2], gt_boxes[g * 5 + 3]);
    __syncthreads();                               // B2

    if (nv <= NFAST) {
        // ===== FAST PATH: 4 independent wave roles, compact-space NMS =====
        float4 b0 = make_float4(0,0,0,0), b1 = make_float4(0,0,0,0);
        float s0 = 0.0f, s1 = 0.0f;
        u64 kw0 = 0, kw1 = 0;

        if (wid == 0) {
            // ---- decode own slots, then priority-space S-matrix + Jacobi
            s0 = (lane < nv)      ? vsc[lane]      : 0.0f;
            s1 = (64 + lane < nv) ? vsc[64 + lane] : 0.0f;
            int idx0 = (lane < nv)      ? vidx[lane]      : 0;
            int idx1 = (64 + lane < nv) ? vidx[64 + lane] : 0;
            DECODE_IDX(idx0, b0)
            DECODE_IDX(idx1, b1)
            float ar0 = (b0.z - b0.x) * (b0.w - b0.y);
            float ar1 = (b1.z - b1.x) * (b1.w - b1.y);
            // S masks: bit i set if box i has higher priority AND IoU > T.
            // priority(i) > priority(j)  <=>  s_i > s_j  ||  (s_i==s_j && i<j)
            u64 S0lo = 0, S0hi = 0, S1lo = 0, S1hi = 0;
            for (int i = 0; i < nv; ++i) {
                bool hi = i >= 64;
                int src = i & 63;
                float cx1 = __shfl(hi ? b1.x : b0.x, src);
                float cy1 = __shfl(hi ? b1.y : b0.y, src);
                float cx2 = __shfl(hi ? b1.z : b0.z, src);
                float cy2 = __shfl(hi ? b1.w : b0.w, src);
                float cs  = __shfl(hi ? s1   : s0,   src);
                float car = (cx2 - cx1) * (cy2 - cy1);
                float i0 = iou_f(cx1, cy1, cx2, cy2, car, b0.x, b0.y, b0.z, b0.w, ar0);
                float i1 = iou_f(cx1, cy1, cx2, cy2, car, b1.x, b1.y, b1.z, b1.w, ar1);
                bool hp0 = (cs > s0) || (cs == s0 && i < lane);       // vs slot lane
                bool hp1 = (cs > s1) || (cs == s1 && i < 64 + lane);  // vs slot 64+lane
                bool sup0 = (i0 > NMS_T) && hp0;
                bool sup1 = (i1 > NMS_T) && hp1;
                if (i < 64) {
                    S0lo |= sup0 ? (1ULL << i) : 0ULL;
                    S1lo |= sup1 ? (1ULL << i) : 0ULL;
                } else {
                    S0hi |= sup0 ? (1ULL << (i - 64)) : 0ULL;
                    S1hi |= sup1 ? (1ULL << (i - 64)) : 0ULL;
                }
            }
            // Jacobi to the unique greedy fixpoint (compact space)
            bool init0 = lane < nv, init1 = 64 + lane < nv;
            kw0 = __ballot(init0); kw1 = __ballot(init1);
            for (int it = 0; it < NFAST; ++it) {
                bool a0 = init0 && !((S0lo & kw0) | (S0hi & kw1));
                bool a1 = init1 && !((S1lo & kw0) | (S1hi & kw1));
                u64 nk0 = __ballot(a0), nk1 = __ballot(a1);
                bool done = (nk0 == kw0) && (nk1 == kw1);
                kw0 = nk0; kw1 = nk1;
                if (done) break;
            }
        } else if (wid == 1 || wid == 2) {
            // ---- GT dedup on own slots (redundant decode, no wave0 dep)
            int e = (wid - 1) * 64 + lane;
            bool has = e < nv;
            int idx = has ? vidx[e] : 0;
            float4 a;
            DECODE_IDX(idx, a)
            bool dup = false;
            if (has) {
                float aarea = (a.z - a.x) * (a.w - a.y);
                for (int g = 0; g < ng; ++g) {
                    float4 gb = sgt[g];
                    float garea = (gb.z - gb.x) * (gb.w - gb.y);
                    dup |= iou_f(a.x, a.y, a.z, a.w, aarea,
                                 gb.x, gb.y, gb.z, gb.w, garea) > DEDUP_T;
                }
            }
            u64 wd = __ballot(dup);
            if (lane == 0) dupw[wid - 1] = wd;
        } else {
            // ---- wave 3: output ranks (row index = rank among valid)
            float t0 = (lane < nv)      ? vsc[lane]      : 0.0f;
            float t1 = (64 + lane < nv) ? vsc[64 + lane] : 0.0f;
            int r0 = 0, r1 = 0;
            const int n0 = nv < 64 ? nv : 64;
            for (int u = 0; u < n0; ++u) {
                float su0 = __shfl(t0, u);
                float su1 = __shfl(t1, u);
                r0 += (su0 > t0) || (su0 == t0 && u < lane);
                r1 += (su0 > t1) || (su0 == t1);
                if (64 + u < nv) {
                    r0 += (su1 > t0);
                    r1 += (su1 > t1) || (su1 == t1 && u < lane);
                }
            }
            if (lane < nv)      rrank[lane]      = r0;
            if (64 + lane < nv) rrank[64 + lane] = r1;
            if (nv <= 64 && lane == 0) dupw[1] = 0ULL;  // ensure defined
        }

        // waves 1-3: zero-fill this class's output (overlaps wave0's NMS;
        // B4's vmcnt drain orders these stores before wave0's kept writes)
        if (wid != 0) {
            float4* o4 = (float4*)o;                 // 2560 float4 per class
            float4 z4 = make_float4(0.f, 0.f, 0.f, 0.f);
            for (int t = (wid - 1) * 64 + lane; t < N_ROIS * 5 / 4; t += 192)
                o4[t] = z4;
        }
        __syncthreads();                             // B4

        // ---- wave 0: write kept rows straight from registers
        if (wid == 0) {
            u64 d0 = dupw[0], d1 = dupw[1];
            if (lane < nv && ((kw0 >> lane) & 1ULL) && !((d0 >> lane) & 1ULL)) {
                float* orow = o + rrank[lane] * 5;
                orow[0] = b0.x; orow[1] = b0.y; orow[2] = b0.z; orow[3] = b0.w;
                orow[4] = s0;
            }
            if (64 + lane < nv && ((kw1 >> lane) & 1ULL) && !((d1 >> lane) & 1ULL)) {
                float* orow = o + rrank[64 + lane] * 5;
                orow[0] = b1.x; orow[1] = b1.y; orow[2] = b1.z; orow[3] = b1.w;
                orow[4] = s1;
            }
        }
        return;
    }

    // ========== FALLBACK (nv > 128): barrier-per-row greedy, full write ==========
    for (int v = tid; v < nv; v += NT) {
        int idx = vidx[v];
        float sc = vsc[v];
        int r = 0;
        for (int u = 0; u < nv; ++u) {
            float su = vsc[u];
            r += (su > sc) || (su == sc && u < v);
        }
        float4 b;
        DECODE_IDX(idx, b)
        sbox[r] = b;
        ssc[r]  = sc;
        keepb[r] = 1;
    }
    __syncthreads();

    for (int i = 0; i < nv; ++i) {
        __syncthreads();
        if (keepb[i]) {
            float4 a = sbox[i];
            float aarea = (a.z - a.x) * (a.w - a.y);
            for (int j = i + 1 + tid; j < nv; j += NT) {
                if (keepb[j]) {
                    float4 bb = sbox[j];
                    float barea = (bb.z - bb.x) * (bb.w - bb.y);
                    if (iou_f(a.x, a.y, a.z, a.w, aarea,
                              bb.x, bb.y, bb.z, bb.w, barea) > NMS_T)
                        keepb[j] = 0;
                }
            }
        }
    }
    __syncthreads();
    for (int v = tid; v < nv; v += NT) {
        if (keepb[v]) {
            float4 a = sbox[v];
            float aarea = (a.z - a.x) * (a.w - a.y);
            bool dup = false;
            for (int g = 0; g < ng; ++g) {
                float4 gb = sgt[g];
                float garea = (gb.z - gb.x) * (gb.w - gb.y);
                dup |= iou_f(a.x, a.y, a.z, a.w, aarea,
                             gb.x, gb.y, gb.z, gb.w, garea) > DEDUP_T;
            }
            if (dup) keepb[v] = 0;
        }
    }
    __syncthreads();
    for (int t = tid; t < N_ROIS * 5; t += NT) {
        int j = t / 5, comp = t - 5 * j;
        float val = 0.0f;
        if (j < nv && keepb[j]) {
            float4 b = sbox[j];
            val = comp == 0 ? b.x : comp == 1 ? b.y : comp == 2 ? b.z :
                  comp == 3 ? b.w : ssc[j];
        }
        o[t] = val;
    }
}

extern "C" void kernel_launch(void* const* d_in, const int* in_sizes, int n_in,
                              void* d_out, int out_size, void* d_ws, size_t ws_size,
                              hipStream_t stream) {
    const float* rois      = (const float*)d_in[0];
    const float* cls_prob  = (const float*)d_in[1];
    const float* bbox_pred = (const float*)d_in[2];
    const float* im_info   = (const float*)d_in[3];
    const float* gt        = (const float*)d_in[4];
    const int*   nb        = (const int*)d_in[5];
    float* out = (float*)d_out;

    detect_kernel<<<dim3(N_CLS_OUT), dim3(NT), 0, stream>>>(
        rois, cls_prob, bbox_pred, im_info, gt, nb, out);
}